// Round 1
// baseline (394.614 us; speedup 1.0000x reference)
//
#include <hip/hip_runtime.h>
#include <math.h>

#define BB 2
#define DIMC 256
#define FF 4
#define HH 16
#define WW 16
#define GRP 4
#define CPG 64        // DIM/GROUPS
#define ODIM 128      // OFF_DIMS
#define PQ 1024       // F*H*W
#define FD 2
#define HD8 8
#define WD8 8
#define PJ 128        // FD*HD*WD
#define NBG 8         // B*GROUPS
#define NHEADS 8
#define DHEAD 64
#define INNERC 512

// ---------------- q = grouped 1x1 conv ----------------
// q[bg][o][p] = sum_i x[b, g*64+i, p] * wq[g,o,i]
__global__ void k_q(const float* __restrict__ x, const float* __restrict__ wq,
                    float* __restrict__ q) {
    int t = blockIdx.x * blockDim.x + threadIdx.x;   // 8*128*1024
    int p = t & 1023;
    int o = (t >> 10) & 127;
    int bg = t >> 17;
    int b = bg >> 2, g = bg & 3;
    const float* xp = x + (size_t)(b * DIMC + g * CPG) * PQ + p;
    const float* wp = wq + (size_t)(g * ODIM + o) * CPG;
    float acc = 0.f;
    #pragma unroll
    for (int i = 0; i < CPG; ++i) acc += xp[i * PQ] * wp[i];
    q[t] = acc;
}

// ---------------- depthwise strided conv + bias + exact GELU ----------------
// act[bg][c][j], j = (zo*8+yo)*8+xo over (2,8,8)
__global__ void k_dw(const float* __restrict__ q, const float* __restrict__ dww,
                     const float* __restrict__ dwb, float* __restrict__ act) {
    int t = blockIdx.x * blockDim.x + threadIdx.x;   // 8*128*128
    int j = t & 127;
    int c = (t >> 7) & 127;
    int bg = t >> 14;
    int xo = j & 7, yo = (j >> 3) & 7, zo = j >> 6;
    const float* qp = q + (size_t)(bg * ODIM + c) * PQ;
    const float* wp = dww + c * 64;
    float acc = dwb[c];
    #pragma unroll
    for (int kz = 0; kz < 4; ++kz) {
        int z = 2 * zo - 1 + kz;
        if (z < 0 || z >= FF) continue;
        #pragma unroll
        for (int ky = 0; ky < 4; ++ky) {
            int y = 2 * yo - 1 + ky;
            if (y < 0 || y >= HH) continue;
            #pragma unroll
            for (int kx = 0; kx < 4; ++kx) {
                int xx = 2 * xo - 1 + kx;
                if (xx < 0 || xx >= WW) continue;
                acc += qp[(z * HH + y) * WW + xx] * wp[(kz * 4 + ky) * 4 + kx];
            }
        }
    }
    // exact GELU: x * 0.5 * (1 + erf(x/sqrt(2)))
    act[t] = 0.5f * acc * (1.0f + erff(acc * 0.70710678118654752f));
}

// ---------------- pointwise 3x128 + tanh*2 + build sampling grid ----------------
// gkv[bg][j][3] : normalized coords in (f,h,w) channel order, norm by (fd-1,hd-1,wd-1)=(1,7,7)
__global__ void k_off(const float* __restrict__ act, const float* __restrict__ pw,
                      float* __restrict__ gkv) {
    int t = blockIdx.x * blockDim.x + threadIdx.x;   // 8*128
    if (t >= NBG * PJ) return;
    int j = t & 127, bg = t >> 7;
    const float* ap = act + (size_t)bg * ODIM * PJ + j;
    float s0 = 0.f, s1 = 0.f, s2 = 0.f;
    for (int c = 0; c < ODIM; ++c) {
        float a = ap[c * PJ];
        s0 += a * pw[0 * ODIM + c];
        s1 += a * pw[1 * ODIM + c];
        s2 += a * pw[2 * ODIM + c];
    }
    float xo = (float)(j & 7), yo = (float)((j >> 3) & 7), zo = (float)(j >> 6);
    float vf = zo + 2.f * tanhf(s0);
    float vh = yo + 2.f * tanhf(s1);
    float vw = xo + 2.f * tanhf(s2);
    gkv[t * 3 + 0] = 2.f * vf / 1.f - 1.f;
    gkv[t * 3 + 1] = 2.f * vh / 7.f - 1.f;
    gkv[t * 3 + 2] = 2.f * vw / 7.f - 1.f;
}

// ---------------- trilinear grid sample (zeros padding, align_corners=False) ----------
// BUG-COMPATIBLE with reference: grid[...,0] (f-coord) -> x/W axis, grid[...,1] -> y/H,
// grid[...,2] (w-coord) -> z/D axis.
__global__ void k_sample(const float* __restrict__ x, const float* __restrict__ gkv,
                         float* __restrict__ kv) {
    int blk = blockIdx.x;            // bg*128 + j
    int c = threadIdx.x;             // 0..63
    int j = blk & 127, bg = blk >> 7;
    int b = bg >> 2, g = bg & 3;
    float g0 = gkv[blk * 3 + 0], g1 = gkv[blk * 3 + 1], g2 = gkv[blk * 3 + 2];
    float ix = ((g0 + 1.f) * WW - 1.f) * 0.5f;
    float iy = ((g1 + 1.f) * HH - 1.f) * 0.5f;
    float iz = ((g2 + 1.f) * FF - 1.f) * 0.5f;
    float x0f = floorf(ix), y0f = floorf(iy), z0f = floorf(iz);
    float tx = ix - x0f, ty = iy - y0f, tz = iz - z0f;
    int x0 = (int)x0f, y0 = (int)y0f, z0 = (int)z0f;
    const float* vol = x + (size_t)(b * DIMC + g * CPG + c) * PQ;
    float acc = 0.f;
    #pragma unroll
    for (int dz = 0; dz < 2; ++dz) {
        int zc = z0 + dz;
        if (zc < 0 || zc >= FF) continue;
        float wz = dz ? tz : 1.f - tz;
        #pragma unroll
        for (int dy = 0; dy < 2; ++dy) {
            int yc = y0 + dy;
            if (yc < 0 || yc >= HH) continue;
            float wy = dy ? ty : 1.f - ty;
            #pragma unroll
            for (int dx = 0; dx < 2; ++dx) {
                int xc = x0 + dx;
                if (xc < 0 || xc >= WW) continue;
                float wgt = wz * wy * (dx ? tx : 1.f - tx);
                acc += vol[(zc * HH + yc) * WW + xc] * wgt;
            }
        }
    }
    kv[(size_t)(bg * CPG + c) * PJ + j] = acc;
}

// ---------------- k, v = grouped 1x1 conv on sampled features ----------------
__global__ void k_kv(const float* __restrict__ kv, const float* __restrict__ wk,
                     const float* __restrict__ wv, float* __restrict__ kk,
                     float* __restrict__ vv) {
    int t = blockIdx.x * blockDim.x + threadIdx.x;   // 8*128*128
    int j = t & 127;
    int o = (t >> 7) & 127;
    int bg = t >> 14;
    int g = bg & 3;
    const float* kp = kv + (size_t)bg * CPG * PJ + j;
    const float* wkp = wk + (size_t)(g * ODIM + o) * CPG;
    const float* wvp = wv + (size_t)(g * ODIM + o) * CPG;
    float ak = 0.f, av = 0.f;
    #pragma unroll
    for (int i = 0; i < CPG; ++i) {
        float val = kp[i * PJ];
        ak += val * wkp[i];
        av += val * wvp[i];
    }
    kk[t] = ak;
    vv[t] = av;
}

// ---------------- fused CPB MLP + QK^T + softmax + attn*V ----------------
// one block per (bg, i); 128 threads = one per j
__global__ __launch_bounds__(128) void k_attn(
    const float* __restrict__ q, const float* __restrict__ kk,
    const float* __restrict__ vv, const float* __restrict__ gkv,
    const float* __restrict__ w0, const float* __restrict__ b0,
    const float* __restrict__ w1, const float* __restrict__ b1,
    const float* __restrict__ w2, const float* __restrict__ b2,
    float* __restrict__ outh) {
    __shared__ float w1s[64 * 64];   // transposed: w1s[jj*64+k] = w1[k*64+jj]
    __shared__ float qs[2 * 64];
    __shared__ float att[2 * 128];
    __shared__ float red[4];

    int blk = blockIdx.x;            // bg*1024 + i
    int i = blk & 1023, bg = blk >> 10;
    int b = bg >> 2, g = bg & 3;
    int tid = threadIdx.x;           // 0..127

    for (int t = tid; t < 64 * 64; t += 128) {
        int jj = t >> 6, k2 = t & 63;
        w1s[t] = w1[k2 * 64 + jj];
    }
    {
        int e = tid >> 6, d = tid & 63;
        qs[tid] = q[(size_t)(bg * ODIM + e * 64 + d) * PQ + i] * 0.125f;
    }
    __syncthreads();

    int j = tid;
    // grid_q for this i (norm by (3,15,15))
    int wq_ = i & 15, hq = (i >> 4) & 15, fq = i >> 8;
    float p0 = (2.f * fq / 3.f - 1.f)  - gkv[(bg * PJ + j) * 3 + 0];
    float p1 = (2.f * hq / 15.f - 1.f) - gkv[(bg * PJ + j) * 3 + 1];
    float p2 = (2.f * wq_ / 15.f - 1.f) - gkv[(bg * PJ + j) * 3 + 2];
    float t0 = copysignf(log1pf(fabsf(p0)), p0);
    float t1 = copysignf(log1pf(fabsf(p1)), p1);
    float t2 = copysignf(log1pf(fabsf(p2)), p2);

    float h0[64];
    #pragma unroll
    for (int k2 = 0; k2 < 64; ++k2) {
        float a = t0 * w0[k2] + t1 * w0[64 + k2] + t2 * w0[128 + k2] + b0[k2];
        h0[k2] = fmaxf(a, 0.f);
    }
    float o2a = b2[0], o2b = b2[1];
    for (int jj = 0; jj < 64; ++jj) {
        float a = b1[jj];
        const float* wr = &w1s[jj * 64];
        #pragma unroll
        for (int k2 = 0; k2 < 64; ++k2) a += h0[k2] * wr[k2];
        a = fmaxf(a, 0.f);
        o2a += a * w2[jj * 2 + 0];
        o2b += a * w2[jj * 2 + 1];
    }

    // sim + bias for both heads of this group
    float s[2];
    #pragma unroll
    for (int e = 0; e < 2; ++e) {
        float acc = (e == 0) ? o2a : o2b;
        const float* kp = kk + (size_t)(bg * ODIM + e * 64) * PJ + j;
        #pragma unroll
        for (int d = 0; d < 64; ++d) acc += qs[e * 64 + d] * kp[d * PJ];
        s[e] = acc;
    }

    att[0 * 128 + j] = s[0];
    att[1 * 128 + j] = s[1];
    __syncthreads();

    // per-wave softmax reduction: wave wv handles row wv
    {
        int wv_ = tid >> 6, ln = tid & 63;
        float a0 = att[wv_ * 128 + ln], a1 = att[wv_ * 128 + 64 + ln];
        float mx = fmaxf(a0, a1);
        for (int off = 32; off; off >>= 1) mx = fmaxf(mx, __shfl_xor(mx, off));
        float ex = expf(a0 - mx) + expf(a1 - mx);
        for (int off = 32; off; off >>= 1) ex += __shfl_xor(ex, off);
        if (ln == 0) { red[wv_ * 2 + 0] = mx; red[wv_ * 2 + 1] = ex; }
    }
    __syncthreads();
    float m0 = red[0], inv0 = 1.f / red[1];
    float m1 = red[2], inv1 = 1.f / red[3];
    float a0n = expf(s[0] - m0) * inv0;
    float a1n = expf(s[1] - m1) * inv1;
    __syncthreads();   // make sure raw s reads done before overwrite
    att[0 * 128 + j] = a0n;
    att[1 * 128 + j] = a1n;
    __syncthreads();

    // attn * V : thread (e,d)
    {
        int e = tid >> 6, d = tid & 63;
        const float* vp = vv + (size_t)(bg * ODIM + e * 64 + d) * PJ;
        float acc = 0.f;
        #pragma unroll
        for (int jj = 0; jj < 128; ++jj) acc += att[e * 128 + jj] * vp[jj];
        outh[(size_t)(b * INNERC + (g * 2 + e) * 64 + d) * PQ + i] = acc;
    }
}

// ---------------- final projection ----------------
__global__ void k_out(const float* __restrict__ outh, const float* __restrict__ wo,
                      const float* __restrict__ bo, float* __restrict__ out) {
    int t = blockIdx.x * blockDim.x + threadIdx.x;   // 2*256*1024
    int p = t & 1023;
    int o = (t >> 10) & 255;
    int b = t >> 18;
    const float* hp = outh + (size_t)b * INNERC * PQ + p;
    const float* wp = wo + (size_t)o * INNERC;
    float acc = bo[o];
    #pragma unroll 8
    for (int c = 0; c < INNERC; ++c) acc += hp[c * PQ] * wp[c];
    out[t] = acc;
}

extern "C" void kernel_launch(void* const* d_in, const int* in_sizes, int n_in,
                              void* d_out, int out_size, void* d_ws, size_t ws_size,
                              hipStream_t stream) {
    const float* x   = (const float*)d_in[0];
    const float* wq  = (const float*)d_in[1];
    const float* wk  = (const float*)d_in[2];
    const float* wv  = (const float*)d_in[3];
    const float* dww = (const float*)d_in[4];
    const float* dwb = (const float*)d_in[5];
    const float* pw  = (const float*)d_in[6];
    const float* w0  = (const float*)d_in[7];
    const float* b0  = (const float*)d_in[8];
    const float* w1  = (const float*)d_in[9];
    const float* b1  = (const float*)d_in[10];
    const float* w2  = (const float*)d_in[11];
    const float* b2  = (const float*)d_in[12];
    const float* wo  = (const float*)d_in[13];
    const float* bo  = (const float*)d_in[14];
    float* out = (float*)d_out;

    float* ws_f = (float*)d_ws;
    float* q    = ws_f;                  // 8*128*1024   = 1048576
    float* act  = q + 1048576;           // 8*128*128    = 131072
    float* gkv  = act + 131072;          // 8*128*3      = 3072
    float* kvb  = gkv + 3072;            // 8*64*128     = 65536
    float* kkb  = kvb + 65536;           // 8*128*128    = 131072
    float* vvb  = kkb + 131072;          // 8*128*128    = 131072
    float* outh = vvb + 131072;          // 2*512*1024   = 1048576

    k_q<<<4096, 256, 0, stream>>>(x, wq, q);
    k_dw<<<512, 256, 0, stream>>>(q, dww, dwb, act);
    k_off<<<4, 256, 0, stream>>>(act, pw, gkv);
    k_sample<<<1024, 64, 0, stream>>>(x, gkv, kvb);
    k_kv<<<512, 256, 0, stream>>>(kvb, wk, wv, kkb, vvb);
    k_attn<<<8192, 128, 0, stream>>>(q, kkb, vvb, gkv, w0, b0, w1, b1, w2, b2, outh);
    k_out<<<2048, 256, 0, stream>>>(outh, wo, bo, out);
}

// Round 2
// 270.149 us; speedup vs baseline: 1.4607x; 1.4607x over previous
//
#include <hip/hip_runtime.h>
#include <math.h>

#define BB 2
#define DIMC 256
#define FF 4
#define HH 16
#define WW 16
#define GRP 4
#define CPG 64        // DIM/GROUPS
#define ODIM 128      // OFF_DIMS
#define PQ 1024       // F*H*W
#define PJ 128        // FD*HD*WD
#define NBG 8         // B*GROUPS
#define INNERC 512

typedef short bf16x8 __attribute__((ext_vector_type(8)));
typedef float f32x4 __attribute__((ext_vector_type(4)));

__device__ __forceinline__ unsigned int bfbits(float x) {
    union { float f; unsigned int u; } v; v.f = x;
    unsigned int u = v.u;
    unsigned int r = u + 0x7fffu + ((u >> 16) & 1u);
    return r >> 16;
}

// ---------------- q = grouped 1x1 conv ----------------
__global__ void k_q(const float* __restrict__ x, const float* __restrict__ wq,
                    float* __restrict__ q) {
    int t = blockIdx.x * blockDim.x + threadIdx.x;   // 8*128*1024
    int p = t & 1023;
    int o = (t >> 10) & 127;
    int bg = t >> 17;
    int b = bg >> 2, g = bg & 3;
    const float* xp = x + (size_t)(b * DIMC + g * CPG) * PQ + p;
    const float* wp = wq + (size_t)(g * ODIM + o) * CPG;
    float acc = 0.f;
    #pragma unroll
    for (int i = 0; i < CPG; ++i) acc += xp[i * PQ] * wp[i];
    q[t] = acc;
}

// ---------------- depthwise strided conv + bias + exact GELU ----------------
__global__ void k_dw(const float* __restrict__ q, const float* __restrict__ dww,
                     const float* __restrict__ dwb, float* __restrict__ act) {
    int t = blockIdx.x * blockDim.x + threadIdx.x;   // 8*128*128
    int j = t & 127;
    int c = (t >> 7) & 127;
    int bg = t >> 14;
    int xo = j & 7, yo = (j >> 3) & 7, zo = j >> 6;
    const float* qp = q + (size_t)(bg * ODIM + c) * PQ;
    const float* wp = dww + c * 64;
    float acc = dwb[c];
    #pragma unroll
    for (int kz = 0; kz < 4; ++kz) {
        int z = 2 * zo - 1 + kz;
        if (z < 0 || z >= FF) continue;
        #pragma unroll
        for (int ky = 0; ky < 4; ++ky) {
            int y = 2 * yo - 1 + ky;
            if (y < 0 || y >= HH) continue;
            #pragma unroll
            for (int kx = 0; kx < 4; ++kx) {
                int xx = 2 * xo - 1 + kx;
                if (xx < 0 || xx >= WW) continue;
                acc += qp[(z * HH + y) * WW + xx] * wp[(kz * 4 + ky) * 4 + kx];
            }
        }
    }
    act[t] = 0.5f * acc * (1.0f + erff(acc * 0.70710678118654752f));
}

// ---------------- pointwise 3x128 + tanh*2 + build sampling grid ----------------
__global__ void k_off(const float* __restrict__ act, const float* __restrict__ pw,
                      float* __restrict__ gkv) {
    int t = blockIdx.x * blockDim.x + threadIdx.x;   // 8*128
    if (t >= NBG * PJ) return;
    int j = t & 127, bg = t >> 7;
    const float* ap = act + (size_t)bg * ODIM * PJ + j;
    float s0 = 0.f, s1 = 0.f, s2 = 0.f;
    for (int c = 0; c < ODIM; ++c) {
        float a = ap[c * PJ];
        s0 += a * pw[0 * ODIM + c];
        s1 += a * pw[1 * ODIM + c];
        s2 += a * pw[2 * ODIM + c];
    }
    float xo = (float)(j & 7), yo = (float)((j >> 3) & 7), zo = (float)(j >> 6);
    float vf = zo + 2.f * tanhf(s0);
    float vh = yo + 2.f * tanhf(s1);
    float vw = xo + 2.f * tanhf(s2);
    gkv[t * 3 + 0] = 2.f * vf / 1.f - 1.f;
    gkv[t * 3 + 1] = 2.f * vh / 7.f - 1.f;
    gkv[t * 3 + 2] = 2.f * vw / 7.f - 1.f;
}

// ---------------- trilinear grid sample (zeros pad, align_corners=False) -------
// BUG-COMPATIBLE: grid ch0 (f-coord) -> x/W axis, ch1 -> y/H, ch2 (w) -> z/D.
__global__ void k_sample(const float* __restrict__ x, const float* __restrict__ gkv,
                         float* __restrict__ kv) {
    int blk = blockIdx.x;            // bg*128 + j
    int c = threadIdx.x;             // 0..63
    int j = blk & 127, bg = blk >> 7;
    int b = bg >> 2, g = bg & 3;
    float g0 = gkv[blk * 3 + 0], g1 = gkv[blk * 3 + 1], g2 = gkv[blk * 3 + 2];
    float ix = ((g0 + 1.f) * WW - 1.f) * 0.5f;
    float iy = ((g1 + 1.f) * HH - 1.f) * 0.5f;
    float iz = ((g2 + 1.f) * FF - 1.f) * 0.5f;
    float x0f = floorf(ix), y0f = floorf(iy), z0f = floorf(iz);
    float tx = ix - x0f, ty = iy - y0f, tz = iz - z0f;
    int x0 = (int)x0f, y0 = (int)y0f, z0 = (int)z0f;
    const float* vol = x + (size_t)(b * DIMC + g * CPG + c) * PQ;
    float acc = 0.f;
    #pragma unroll
    for (int dz = 0; dz < 2; ++dz) {
        int zc = z0 + dz;
        if (zc < 0 || zc >= FF) continue;
        float wz = dz ? tz : 1.f - tz;
        #pragma unroll
        for (int dy = 0; dy < 2; ++dy) {
            int yc = y0 + dy;
            if (yc < 0 || yc >= HH) continue;
            float wy = dy ? ty : 1.f - ty;
            #pragma unroll
            for (int dx = 0; dx < 2; ++dx) {
                int xc = x0 + dx;
                if (xc < 0 || xc >= WW) continue;
                float wgt = wz * wy * (dx ? tx : 1.f - tx);
                acc += vol[(zc * HH + yc) * WW + xc] * wgt;
            }
        }
    }
    kv[(size_t)(bg * CPG + c) * PJ + j] = acc;
}

// ---------------- k projection: kk[bg][o][j] (lane=j, coalesced) ----------------
__global__ void k_k(const float* __restrict__ kv, const float* __restrict__ wk,
                    float* __restrict__ kk) {
    int t = blockIdx.x * blockDim.x + threadIdx.x;   // 8*128*128
    int j = t & 127;
    int o = (t >> 7) & 127;
    int bg = t >> 14;
    int g = bg & 3;
    const float* kp = kv + (size_t)bg * CPG * PJ + j;
    const float* wkp = wk + (size_t)(g * ODIM + o) * CPG;
    float ak = 0.f;
    #pragma unroll
    for (int i = 0; i < CPG; ++i) ak += kp[i * PJ] * wkp[i];
    kk[t] = ak;
}

// ---------------- v projection transposed: vvT[bg][j][o] (lane=o, coalesced) ----
__global__ void k_v(const float* __restrict__ kv, const float* __restrict__ wv,
                    float* __restrict__ vvT) {
    int t = blockIdx.x * blockDim.x + threadIdx.x;   // 8*128*128
    int o = t & 127;
    int j = (t >> 7) & 127;
    int bg = t >> 14;
    int g = bg & 3;
    const float* kp = kv + (size_t)bg * CPG * PJ + j;   // uniform j per wave -> broadcast
    const float* wvp = wv + (size_t)(g * ODIM + o) * CPG;
    float av = 0.f;
    #pragma unroll
    for (int i = 0; i < CPG; ++i) av += kp[i * PJ] * wvp[i];
    vvT[(size_t)(bg * PJ + j) * ODIM + o] = av;
}

// ---------------- pre-pack W1 into B-fragment order (bf16) ----------------
// wb[(kc*4+nt)*64 + lane] holds 8 bf16: W1[k][n], n=nt*16+(lane&15),
// k = kc*32 + (lane>>4)*8 + idx, idx=0..7
__global__ void k_pack(const float* __restrict__ w1, uint4* __restrict__ wb) {
    int t = blockIdx.x * blockDim.x + threadIdx.x;
    if (t >= 512) return;
    int lane = t & 63, nt = (t >> 6) & 3, kc = t >> 8;
    int n = nt * 16 + (lane & 15);
    int kbase = kc * 32 + (lane >> 4) * 8;
    unsigned int pk[4];
    #pragma unroll
    for (int p = 0; p < 4; ++p) {
        unsigned int lo = bfbits(w1[(kbase + 2 * p) * 64 + n]);
        unsigned int hi = bfbits(w1[(kbase + 2 * p + 1) * 64 + n]);
        pk[p] = lo | (hi << 16);
    }
    wb[(kc * 4 + nt) * 64 + lane] = make_uint4(pk[0], pk[1], pk[2], pk[3]);
}

// ---------------- fused CPB MLP (MFMA layer-1) + QK^T + softmax + attn*V -------
// one block per (bg, i); 128 threads = 2 waves; thread j in [0,128)
__global__ __launch_bounds__(128) void k_attn(
    const float* __restrict__ q, const float* __restrict__ kk,
    const float* __restrict__ vvT, const float* __restrict__ gkv,
    const float* __restrict__ w0, const float* __restrict__ b0,
    const uint4* __restrict__ wb, const float* __restrict__ b1,
    const float* __restrict__ w2, const float* __restrict__ b2,
    float* __restrict__ outh) {
    // phase 1: h0s chunk-major [c(8)][j(128)] of uint4 (8 bf16) = 16384 B
    // phase 2 (aliased): part[m(128)][36] f32 = 18432 B
    __shared__ __align__(16) char buf_[18432];
    uint4* h0s = (uint4*)buf_;
    float* part = (float*)buf_;
    __shared__ float qs[128];
    __shared__ float att[256];
    __shared__ float red[4];

    int blk = blockIdx.x;            // bg*1024 + i
    int i = blk & 1023, bg = blk >> 10;
    int b = bg >> 2, g = bg & 3;
    int tid = threadIdx.x;           // 0..127
    int w = tid >> 6, lane = tid & 63, col = lane & 15, quad = lane >> 4;

    // B fragments: block-invariant, L2-hot
    uint4 bfr[2][4];
    #pragma unroll
    for (int kc = 0; kc < 2; ++kc)
        #pragma unroll
        for (int nt = 0; nt < 4; ++nt)
            bfr[kc][nt] = wb[(kc * 4 + nt) * 64 + lane];

    {
        int e = tid >> 6, d = tid & 63;
        qs[tid] = q[(size_t)(bg * ODIM + e * 64 + d) * PQ + i] * 0.125f;
    }

    int j = tid;
    int wq_ = i & 15, hq = (i >> 4) & 15, fq = i >> 8;
    float p0 = (2.f * fq / 3.f - 1.f)  - gkv[(bg * PJ + j) * 3 + 0];
    float p1 = (2.f * hq / 15.f - 1.f) - gkv[(bg * PJ + j) * 3 + 1];
    float p2 = (2.f * wq_ / 15.f - 1.f) - gkv[(bg * PJ + j) * 3 + 2];
    float t0 = copysignf(log1pf(fabsf(p0)), p0);
    float t1 = copysignf(log1pf(fabsf(p1)), p1);
    float t2 = copysignf(log1pf(fabsf(p2)), p2);

    // h0 = relu(t @ w0 + b0), computed in 8-element chunks, packed bf16 -> LDS
    #pragma unroll
    for (int c = 0; c < 8; ++c) {
        unsigned int pk[4];
        #pragma unroll
        for (int hp = 0; hp < 4; ++hp) {
            int k2 = c * 8 + hp * 2;
            float a0 = fmaxf(t0 * w0[k2] + t1 * w0[64 + k2] + t2 * w0[128 + k2] + b0[k2], 0.f);
            float a1 = fmaxf(t0 * w0[k2 + 1] + t1 * w0[64 + k2 + 1] + t2 * w0[128 + k2 + 1] + b0[k2 + 1], 0.f);
            pk[hp] = bfbits(a0) | (bfbits(a1) << 16);
        }
        h0s[c * 128 + j] = make_uint4(pk[0], pk[1], pk[2], pk[3]);
    }
    __syncthreads();

    // layer-1 GEMM: H1[128 x 64] = H0[128 x 64] @ W1[64 x 64], wave w owns rows w*64..+63
    f32x4 acc[4][4] = {};
    #pragma unroll
    for (int kc = 0; kc < 2; ++kc)
        #pragma unroll
        for (int mt = 0; mt < 4; ++mt) {
            uint4 av = h0s[(kc * 4 + quad) * 128 + (w * 64 + mt * 16 + col)];
            bf16x8 af = *(bf16x8*)&av;
            #pragma unroll
            for (int nt = 0; nt < 4; ++nt)
                acc[mt][nt] = __builtin_amdgcn_mfma_f32_16x16x32_bf16(
                    af, *(bf16x8*)&bfr[kc][nt], acc[mt][nt], 0, 0, 0);
        }
    __syncthreads();   // h0s reads done -> safe to alias as part[]

    // epilogue: o2[m][e] partials; lane holds h1[m=..+quad*4+reg][jj=nt*16+col]
    float b1v[4], w2a[4], w2b[4];
    #pragma unroll
    for (int nt = 0; nt < 4; ++nt) {
        int jj = nt * 16 + col;
        b1v[nt] = b1[jj]; w2a[nt] = w2[jj * 2]; w2b[nt] = w2[jj * 2 + 1];
    }
    #pragma unroll
    for (int mt = 0; mt < 4; ++mt)
        #pragma unroll
        for (int reg = 0; reg < 4; ++reg) {
            float pa = 0.f, pb = 0.f;
            #pragma unroll
            for (int nt = 0; nt < 4; ++nt) {
                float hv = fmaxf(acc[mt][nt][reg] + b1v[nt], 0.f);
                pa += hv * w2a[nt]; pb += hv * w2b[nt];
            }
            int m = w * 64 + mt * 16 + quad * 4 + reg;
            part[m * 36 + col] = pa;
            part[m * 36 + 16 + col] = pb;
        }
    __syncthreads();

    float bias0 = b2[0], bias1 = b2[1];
    {
        const float* pr = &part[j * 36];
        #pragma unroll
        for (int c = 0; c < 16; ++c) { bias0 += pr[c]; bias1 += pr[16 + c]; }
    }

    // QK^T + bias
    float s0 = bias0, s1 = bias1;
    const float* kp0 = kk + (size_t)(bg * ODIM) * PJ + j;
    #pragma unroll
    for (int d = 0; d < 64; ++d) {
        s0 += qs[d] * kp0[d * PJ];
        s1 += qs[64 + d] * kp0[(64 + d) * PJ];
    }

    att[0 * 128 + j] = s0;
    att[1 * 128 + j] = s1;
    __syncthreads();

    // per-wave softmax reduction: wave wv handles head-row wv
    {
        int wv_ = tid >> 6, ln = tid & 63;
        float a0 = att[wv_ * 128 + ln], a1 = att[wv_ * 128 + 64 + ln];
        float mx = fmaxf(a0, a1);
        for (int off = 32; off; off >>= 1) mx = fmaxf(mx, __shfl_xor(mx, off));
        float ex = expf(a0 - mx) + expf(a1 - mx);
        for (int off = 32; off; off >>= 1) ex += __shfl_xor(ex, off);
        if (ln == 0) { red[wv_ * 2 + 0] = mx; red[wv_ * 2 + 1] = ex; }
    }
    __syncthreads();
    float m0 = red[0], inv0 = 1.f / red[1];
    float m1 = red[2], inv1 = 1.f / red[3];
    float a0n = expf(s0 - m0) * inv0;
    float a1n = expf(s1 - m1) * inv1;
    __syncthreads();
    att[0 * 128 + j] = a0n;
    att[1 * 128 + j] = a1n;
    __syncthreads();

    // attn * V : thread (e,d), vvT coalesced across lanes
    {
        int e = tid >> 6, d = tid & 63;
        const float* vp = vvT + (size_t)bg * PJ * ODIM + e * 64 + d;
        float acc2 = 0.f;
        #pragma unroll
        for (int jj = 0; jj < 128; ++jj) acc2 += att[e * 128 + jj] * vp[(size_t)jj * ODIM];
        outh[(size_t)(b * INNERC + (g * 2 + e) * 64 + d) * PQ + i] = acc2;
    }
}

// ---------------- final projection ----------------
__global__ void k_out(const float* __restrict__ outh, const float* __restrict__ wo,
                      const float* __restrict__ bo, float* __restrict__ out) {
    int t = blockIdx.x * blockDim.x + threadIdx.x;   // 2*256*1024
    int p = t & 1023;
    int o = (t >> 10) & 255;
    int b = t >> 18;
    const float* hp = outh + (size_t)b * INNERC * PQ + p;
    const float* wp = wo + (size_t)o * INNERC;
    float acc = bo[o];
    #pragma unroll 8
    for (int c = 0; c < INNERC; ++c) acc += hp[c * PQ] * wp[c];
    out[t] = acc;
}

extern "C" void kernel_launch(void* const* d_in, const int* in_sizes, int n_in,
                              void* d_out, int out_size, void* d_ws, size_t ws_size,
                              hipStream_t stream) {
    const float* x   = (const float*)d_in[0];
    const float* wq  = (const float*)d_in[1];
    const float* wk  = (const float*)d_in[2];
    const float* wv  = (const float*)d_in[3];
    const float* dww = (const float*)d_in[4];
    const float* dwb = (const float*)d_in[5];
    const float* pw  = (const float*)d_in[6];
    const float* w0  = (const float*)d_in[7];
    const float* b0  = (const float*)d_in[8];
    const float* w1  = (const float*)d_in[9];
    const float* b1  = (const float*)d_in[10];
    const float* w2  = (const float*)d_in[11];
    const float* b2  = (const float*)d_in[12];
    const float* wo  = (const float*)d_in[13];
    const float* bo  = (const float*)d_in[14];
    float* out = (float*)d_out;

    float* ws_f = (float*)d_ws;
    uint4* wb   = (uint4*)ws_f;          // 512 uint4 = 2048 floats
    float* q    = ws_f + 2048;           // 8*128*1024   = 1048576
    float* act  = q + 1048576;           // 8*128*128    = 131072
    float* gkv  = act + 131072;          // 8*128*3      = 3072
    float* kvb  = gkv + 3072;            // 8*64*128     = 65536
    float* kkb  = kvb + 65536;           // 8*128*128    = 131072
    float* vvT  = kkb + 131072;          // 8*128*128    = 131072
    float* outh = vvT + 131072;          // 2*512*1024   = 1048576

    k_pack<<<2, 256, 0, stream>>>(w1, wb);
    k_q<<<4096, 256, 0, stream>>>(x, wq, q);
    k_dw<<<512, 256, 0, stream>>>(q, dww, dwb, act);
    k_off<<<4, 256, 0, stream>>>(act, pw, gkv);
    k_sample<<<1024, 64, 0, stream>>>(x, gkv, kvb);
    k_k<<<512, 256, 0, stream>>>(kvb, wk, kkb);
    k_v<<<512, 256, 0, stream>>>(kvb, wv, vvT);
    k_attn<<<8192, 128, 0, stream>>>(q, kkb, vvT, gkv, w0, b0, wb, b1, w2, b2, outh);
    k_out<<<2048, 256, 0, stream>>>(outh, wo, bo, out);
}

// Round 3
// 269.790 us; speedup vs baseline: 1.4627x; 1.0013x over previous
//
#include <hip/hip_runtime.h>
#include <hip/hip_bf16.h>
#include <math.h>

#define BB 2
#define DIMC 256
#define FF 4
#define HH 16
#define WW 16
#define GRP 4
#define CPG 64        // DIM/GROUPS
#define ODIM 128      // OFF_DIMS
#define PQ 1024       // F*H*W
#define PJ 128        // FD*HD*WD
#define NBG 8         // B*GROUPS
#define INNERC 512

typedef short bf16x8 __attribute__((ext_vector_type(8)));
typedef float f32x4 __attribute__((ext_vector_type(4)));
typedef float f32x2 __attribute__((ext_vector_type(2)));

__device__ __forceinline__ unsigned int bfbits(float x) {
    union { float f; unsigned int u; } v; v.f = x;
    unsigned int u = v.u;
    unsigned int r = u + 0x7fffu + ((u >> 16) & 1u);
    return r >> 16;
}

__device__ __forceinline__ unsigned int pack_bf2(f32x2 a) {
    float2 ff = make_float2(a.x, a.y);
    __hip_bfloat162 h2 = __float22bfloat162_rn(ff);
    union { __hip_bfloat162 h; unsigned int u; } c; c.h = h2;
    return c.u;
}

// ---------------- q = grouped 1x1 conv, 4 outputs/thread ----------------
__global__ void k_q(const float* __restrict__ x, const float* __restrict__ wq,
                    float* __restrict__ q) {
    int t = blockIdx.x * blockDim.x + threadIdx.x;   // 8*32*1024 = 262144
    int p = t & 1023;
    int og = (t >> 10) & 31;     // uniform per 256-thr block
    int bg = t >> 15;
    int b = bg >> 2, g = bg & 3;
    int o0 = og * 4;
    const float* xp = x + (size_t)(b * DIMC + g * CPG) * PQ + p;
    const float* wp = wq + (size_t)(g * ODIM + o0) * CPG;
    float acc[4] = {0.f, 0.f, 0.f, 0.f};
    #pragma unroll 8
    for (int i = 0; i < CPG; ++i) {
        float xv = xp[i * PQ];
        #pragma unroll
        for (int k = 0; k < 4; ++k) acc[k] += xv * wp[k * CPG + i];
    }
    #pragma unroll
    for (int k = 0; k < 4; ++k)
        q[(size_t)(bg * ODIM + o0 + k) * PQ + p] = acc[k];
}

// ---------------- depthwise strided conv + GELU, plus W1 pack tail ----------------
__global__ void k_dwp(const float* __restrict__ q, const float* __restrict__ dww,
                      const float* __restrict__ dwb, float* __restrict__ act,
                      const float* __restrict__ w1, uint4* __restrict__ wb) {
    if (blockIdx.x >= 512) {
        // W1 -> B-fragment bf16 pack (2 blocks)
        int t = (blockIdx.x - 512) * 256 + threadIdx.x;
        if (t < 512) {
            int lane = t & 63, nt = (t >> 6) & 3, kc = t >> 8;
            int n = nt * 16 + (lane & 15);
            int kbase = kc * 32 + (lane >> 4) * 8;
            unsigned int pk[4];
            #pragma unroll
            for (int p = 0; p < 4; ++p) {
                unsigned int lo = bfbits(w1[(kbase + 2 * p) * 64 + n]);
                unsigned int hi = bfbits(w1[(kbase + 2 * p + 1) * 64 + n]);
                pk[p] = lo | (hi << 16);
            }
            wb[(kc * 4 + nt) * 64 + lane] = make_uint4(pk[0], pk[1], pk[2], pk[3]);
        }
        return;
    }
    int t = blockIdx.x * 256 + threadIdx.x;          // 8*128*128
    int j = t & 127;
    int c = (t >> 7) & 127;
    int bg = t >> 14;
    int xo = j & 7, yo = (j >> 3) & 7, zo = j >> 6;
    const float* qp = q + (size_t)(bg * ODIM + c) * PQ;
    const float* wp = dww + c * 64;
    float acc = dwb[c];
    #pragma unroll
    for (int kz = 0; kz < 4; ++kz) {
        int z = 2 * zo - 1 + kz;
        if (z < 0 || z >= FF) continue;
        #pragma unroll
        for (int ky = 0; ky < 4; ++ky) {
            int y = 2 * yo - 1 + ky;
            if (y < 0 || y >= HH) continue;
            #pragma unroll
            for (int kx = 0; kx < 4; ++kx) {
                int xx = 2 * xo - 1 + kx;
                if (xx < 0 || xx >= WW) continue;
                acc += qp[(z * HH + y) * WW + xx] * wp[(kz * 4 + ky) * 4 + kx];
            }
        }
    }
    act[t] = 0.5f * acc * (1.0f + erff(acc * 0.70710678118654752f));
}

// ---------------- pointwise 3x128 + tanh*2 + grid, parallel reduce ----------------
__global__ __launch_bounds__(128) void k_off(const float* __restrict__ act,
                                             const float* __restrict__ pw,
                                             float* __restrict__ gkv) {
    __shared__ float red[6];
    int blk = blockIdx.x;            // bg*128 + j
    int j = blk & 127, bg = blk >> 7;
    int c = threadIdx.x;             // 0..127
    float val = act[(size_t)(bg * ODIM + c) * PJ + j];
    float s0 = val * pw[c];
    float s1 = val * pw[ODIM + c];
    float s2 = val * pw[2 * ODIM + c];
    #pragma unroll
    for (int off = 32; off; off >>= 1) {
        s0 += __shfl_xor(s0, off);
        s1 += __shfl_xor(s1, off);
        s2 += __shfl_xor(s2, off);
    }
    int w = threadIdx.x >> 6;
    if ((threadIdx.x & 63) == 0) { red[w * 3] = s0; red[w * 3 + 1] = s1; red[w * 3 + 2] = s2; }
    __syncthreads();
    if (threadIdx.x == 0) {
        s0 = red[0] + red[3]; s1 = red[1] + red[4]; s2 = red[2] + red[5];
        float xo = (float)(j & 7), yo = (float)((j >> 3) & 7), zo = (float)(j >> 6);
        float vf = zo + 2.f * tanhf(s0);
        float vh = yo + 2.f * tanhf(s1);
        float vw = xo + 2.f * tanhf(s2);
        gkv[blk * 3 + 0] = 2.f * vf - 1.f;
        gkv[blk * 3 + 1] = 2.f * vh / 7.f - 1.f;
        gkv[blk * 3 + 2] = 2.f * vw / 7.f - 1.f;
    }
}

// ---------------- trilinear grid sample (zeros pad, align_corners=False) -------
// BUG-COMPATIBLE: grid ch0 (f-coord) -> x/W axis, ch1 -> y/H, ch2 (w) -> z/D.
__global__ void k_sample(const float* __restrict__ x, const float* __restrict__ gkv,
                         float* __restrict__ kv) {
    int t = blockIdx.x * 256 + threadIdx.x;   // 8*128*64
    int c = t & 63;
    int blk = t >> 6;                // bg*128 + j
    int j = blk & 127, bg = blk >> 7;
    int b = bg >> 2, g = bg & 3;
    float g0 = gkv[blk * 3 + 0], g1 = gkv[blk * 3 + 1], g2 = gkv[blk * 3 + 2];
    float ix = ((g0 + 1.f) * WW - 1.f) * 0.5f;
    float iy = ((g1 + 1.f) * HH - 1.f) * 0.5f;
    float iz = ((g2 + 1.f) * FF - 1.f) * 0.5f;
    float x0f = floorf(ix), y0f = floorf(iy), z0f = floorf(iz);
    float tx = ix - x0f, ty = iy - y0f, tz = iz - z0f;
    int x0 = (int)x0f, y0 = (int)y0f, z0 = (int)z0f;
    const float* vol = x + (size_t)(b * DIMC + g * CPG + c) * PQ;
    float acc = 0.f;
    #pragma unroll
    for (int dz = 0; dz < 2; ++dz) {
        int zc = z0 + dz;
        if (zc < 0 || zc >= FF) continue;
        float wz = dz ? tz : 1.f - tz;
        #pragma unroll
        for (int dy = 0; dy < 2; ++dy) {
            int yc = y0 + dy;
            if (yc < 0 || yc >= HH) continue;
            float wy = dy ? ty : 1.f - ty;
            #pragma unroll
            for (int dx = 0; dx < 2; ++dx) {
                int xc = x0 + dx;
                if (xc < 0 || xc >= WW) continue;
                float wgt = wz * wy * (dx ? tx : 1.f - tx);
                acc += vol[(zc * HH + yc) * WW + xc] * wgt;
            }
        }
    }
    kv[(size_t)(bg * CPG + c) * PJ + j] = acc;
}

// ---------------- k projection, paired layout kk2[bg][d][j][e] ----------------
__global__ void k_k(const float* __restrict__ kv, const float* __restrict__ wk,
                    float* __restrict__ kk2) {
    int t = blockIdx.x * blockDim.x + threadIdx.x;   // 8*128*128
    int j = t & 127;
    int o = (t >> 7) & 127;
    int bg = t >> 14;
    int g = bg & 3;
    const float* kp = kv + (size_t)bg * CPG * PJ + j;
    const float* wkp = wk + (size_t)(g * ODIM + o) * CPG;
    float ak = 0.f;
    #pragma unroll
    for (int i = 0; i < CPG; ++i) ak += kp[i * PJ] * wkp[i];
    kk2[((size_t)(bg * 64 + (o & 63)) * PJ + j) * 2 + (o >> 6)] = ak;
}

// ---------------- v projection, paired layout vvT2[bg][jp][o][par] ----------------
__global__ void k_v(const float* __restrict__ kv, const float* __restrict__ wv,
                    float* __restrict__ vvT2) {
    int t = blockIdx.x * blockDim.x + threadIdx.x;   // 8*128*128
    int o = t & 127;
    int j = (t >> 7) & 127;
    int bg = t >> 14;
    int g = bg & 3;
    const float* kp = kv + (size_t)bg * CPG * PJ + j;   // j uniform per wave -> broadcast
    const float* wvp = wv + (size_t)(g * ODIM + o) * CPG;
    float av = 0.f;
    #pragma unroll
    for (int i = 0; i < CPG; ++i) av += kp[i * PJ] * wvp[i];
    vvT2[((size_t)(bg * 64 + (j >> 1)) * ODIM + o) * 2 + (j & 1)] = av;
}

// ---------------- fused CPB MLP (MFMA layer-1) + QK^T + softmax + attn*V -------
__global__ __launch_bounds__(128) void k_attn(
    const float* __restrict__ q, const float* __restrict__ kk2,
    const float* __restrict__ vvT2, const float* __restrict__ gkv,
    const float* __restrict__ w0, const float* __restrict__ b0,
    const uint4* __restrict__ wb, const float* __restrict__ b1,
    const float* __restrict__ w2, const float* __restrict__ b2,
    float* __restrict__ outh) {
    // phase 1: h0s [8][128] uint4 (16384 B); phase 2 alias: part [128][17] f32x2 (17408 B)
    __shared__ __align__(16) char buf_[17408];
    uint4* h0s = (uint4*)buf_;
    f32x2* part = (f32x2*)buf_;
    __shared__ f32x2 qs2[64];
    __shared__ float att[256];
    __shared__ float red[4];

    int blk = blockIdx.x;            // bg*1024 + i
    int i = blk & 1023, bg = blk >> 10;
    int b = bg >> 2, g = bg & 3;
    int tid = threadIdx.x;           // 0..127
    int w = tid >> 6, lane = tid & 63, col = lane & 15, quad = lane >> 4;

    // W1 B fragments: block-invariant, L2-hot
    uint4 bfr[2][4];
    #pragma unroll
    for (int kc = 0; kc < 2; ++kc)
        #pragma unroll
        for (int nt = 0; nt < 4; ++nt)
            bfr[kc][nt] = wb[(kc * 4 + nt) * 64 + lane];

    {
        int e = tid >> 6, d = tid & 63;
        ((float*)qs2)[d * 2 + e] = q[(size_t)(bg * ODIM + e * 64 + d) * PQ + i] * 0.125f;
    }

    int j = tid;
    int wq_ = i & 15, hq = (i >> 4) & 15, fq = i >> 8;
    float p0 = (2.f * fq / 3.f - 1.f)  - gkv[(bg * PJ + j) * 3 + 0];
    float p1 = (2.f * hq / 15.f - 1.f) - gkv[(bg * PJ + j) * 3 + 1];
    float p2 = (2.f * wq_ / 15.f - 1.f) - gkv[(bg * PJ + j) * 3 + 2];
    float t0 = copysignf(__logf(1.f + fabsf(p0)), p0);
    float t1 = copysignf(__logf(1.f + fabsf(p1)), p1);
    float t2 = copysignf(__logf(1.f + fabsf(p2)), p2);

    // h0 = relu(t @ w0 + b0) in packed-f32 pairs, bf16-packed to LDS
    #pragma unroll
    for (int c = 0; c < 8; ++c) {
        unsigned int pk[4];
        #pragma unroll
        for (int hp = 0; hp < 4; ++hp) {
            int k2 = c * 8 + hp * 2;
            f32x2 a = *(const f32x2*)&b0[k2];
            a += t0 * *(const f32x2*)&w0[k2];
            a += t1 * *(const f32x2*)&w0[64 + k2];
            a += t2 * *(const f32x2*)&w0[128 + k2];
            a.x = fmaxf(a.x, 0.f); a.y = fmaxf(a.y, 0.f);
            pk[hp] = pack_bf2(a);
        }
        h0s[c * 128 + j] = make_uint4(pk[0], pk[1], pk[2], pk[3]);
    }
    __syncthreads();

    // layer-1 GEMM: H1[128x64] = H0[128x64] @ W1[64x64]
    f32x4 acc[4][4] = {};
    #pragma unroll
    for (int kc = 0; kc < 2; ++kc)
        #pragma unroll
        for (int mt = 0; mt < 4; ++mt) {
            uint4 av = h0s[(kc * 4 + quad) * 128 + (w * 64 + mt * 16 + col)];
            bf16x8 af = *(bf16x8*)&av;
            #pragma unroll
            for (int nt = 0; nt < 4; ++nt)
                acc[mt][nt] = __builtin_amdgcn_mfma_f32_16x16x32_bf16(
                    af, *(bf16x8*)&bfr[kc][nt], acc[mt][nt], 0, 0, 0);
        }
    __syncthreads();   // h0s reads done -> alias as part[]

    // epilogue: relu(h1+b1) @ w2 partials, paired (head0, head1)
    float b1v[4]; f32x2 w2v[4];
    #pragma unroll
    for (int nt = 0; nt < 4; ++nt) {
        int jj = nt * 16 + col;
        b1v[nt] = b1[jj];
        w2v[nt] = *(const f32x2*)&w2[jj * 2];
    }
    #pragma unroll
    for (int mt = 0; mt < 4; ++mt)
        #pragma unroll
        for (int reg = 0; reg < 4; ++reg) {
            f32x2 pp = {0.f, 0.f};
            #pragma unroll
            for (int nt = 0; nt < 4; ++nt) {
                float hv = fmaxf(acc[mt][nt][reg] + b1v[nt], 0.f);
                pp += hv * w2v[nt];
            }
            int m = w * 64 + mt * 16 + quad * 4 + reg;
            part[m * 17 + col] = pp;
        }
    __syncthreads();

    f32x2 bias2 = *(const f32x2*)b2;
    {
        const f32x2* pr = &part[j * 17];
        #pragma unroll
        for (int c = 0; c < 16; ++c) bias2 += pr[c];
    }

    // QK^T + bias (paired heads)
    f32x2 s2 = bias2;
    {
        const f32x2* kp = (const f32x2*)kk2 + (size_t)(bg * 64) * PJ + j;
        #pragma unroll 8
        for (int d = 0; d < 64; ++d) s2 += qs2[d] * kp[(size_t)d * PJ];
    }
    att[j] = s2.x;
    att[128 + j] = s2.y;
    __syncthreads();

    {
        int wv_ = tid >> 6, ln = tid & 63;
        float a0 = att[wv_ * 128 + ln], a1 = att[wv_ * 128 + 64 + ln];
        float mx = fmaxf(a0, a1);
        for (int off = 32; off; off >>= 1) mx = fmaxf(mx, __shfl_xor(mx, off));
        float ex = __expf(a0 - mx) + __expf(a1 - mx);
        for (int off = 32; off; off >>= 1) ex += __shfl_xor(ex, off);
        if (ln == 0) { red[wv_ * 2 + 0] = mx; red[wv_ * 2 + 1] = ex; }
    }
    __syncthreads();
    float m0 = red[0], inv0 = 1.f / red[1];
    float m1 = red[2], inv1 = 1.f / red[3];
    float a0n = __expf(s2.x - m0) * inv0;
    float a1n = __expf(s2.y - m1) * inv1;
    __syncthreads();
    att[j] = a0n;
    att[128 + j] = a1n;
    __syncthreads();

    // attn * V, paired j
    {
        int e = tid >> 6, d = tid & 63;
        const f32x2* vp = (const f32x2*)vvT2 + (size_t)(bg * 64) * ODIM + tid;
        const f32x2* ap = (const f32x2*)&att[e * 128];
        f32x2 acc2 = {0.f, 0.f};
        #pragma unroll 8
        for (int jp = 0; jp < 64; ++jp) acc2 += ap[jp] * vp[(size_t)jp * ODIM];
        // outh layout [b][p][c] -> lane-coalesced store
        outh[((size_t)b * PQ + i) * INNERC + (g * 2 + e) * 64 + d] = acc2.x + acc2.y;
    }
}

// ---------------- final projection, 8 outputs/thread, contiguous reads ---------
__global__ void k_out(const float* __restrict__ outh, const float* __restrict__ wo,
                      const float* __restrict__ bo, float* __restrict__ out) {
    int t = blockIdx.x * 256 + threadIdx.x;   // 2*32*1024 = 65536
    int p = t & 1023;
    int og = (t >> 10) & 31;     // uniform per block
    int b = t >> 15;
    int o0 = og * 8;
    const float* hp = outh + ((size_t)b * PQ + p) * INNERC;
    const float* wp = wo + (size_t)o0 * INNERC;
    float acc[8];
    #pragma unroll
    for (int k = 0; k < 8; ++k) acc[k] = bo[o0 + k];
    #pragma unroll 4
    for (int c = 0; c < INNERC; c += 4) {
        float4 hv = *(const float4*)&hp[c];
        #pragma unroll
        for (int k = 0; k < 8; ++k) {
            const float* wr = &wp[k * INNERC + c];
            acc[k] += hv.x * wr[0] + hv.y * wr[1] + hv.z * wr[2] + hv.w * wr[3];
        }
    }
    #pragma unroll
    for (int k = 0; k < 8; ++k)
        out[(size_t)(b * DIMC + o0 + k) * PQ + p] = acc[k];
}

extern "C" void kernel_launch(void* const* d_in, const int* in_sizes, int n_in,
                              void* d_out, int out_size, void* d_ws, size_t ws_size,
                              hipStream_t stream) {
    const float* x   = (const float*)d_in[0];
    const float* wq  = (const float*)d_in[1];
    const float* wk  = (const float*)d_in[2];
    const float* wv  = (const float*)d_in[3];
    const float* dww = (const float*)d_in[4];
    const float* dwb = (const float*)d_in[5];
    const float* pw  = (const float*)d_in[6];
    const float* w0  = (const float*)d_in[7];
    const float* b0  = (const float*)d_in[8];
    const float* w1  = (const float*)d_in[9];
    const float* b1  = (const float*)d_in[10];
    const float* w2  = (const float*)d_in[11];
    const float* b2  = (const float*)d_in[12];
    const float* wo  = (const float*)d_in[13];
    const float* bo  = (const float*)d_in[14];
    float* out = (float*)d_out;

    float* ws_f = (float*)d_ws;
    uint4* wb   = (uint4*)ws_f;          // 2048 floats
    float* q    = ws_f + 2048;           // 1048576
    float* act  = q + 1048576;           // 131072
    float* gkv  = act + 131072;          // 3072
    float* kvb  = gkv + 3072;            // 65536
    float* kk2  = kvb + 65536;           // 131072
    float* vvT2 = kk2 + 131072;          // 131072
    float* outh = vvT2 + 131072;         // 1048576

    k_q<<<1024, 256, 0, stream>>>(x, wq, q);
    k_dwp<<<514, 256, 0, stream>>>(q, dww, dwb, act, w1, wb);
    k_off<<<1024, 128, 0, stream>>>(act, pw, gkv);
    k_sample<<<256, 256, 0, stream>>>(x, gkv, kvb);
    k_k<<<512, 256, 0, stream>>>(kvb, wk, kk2);
    k_v<<<512, 256, 0, stream>>>(kvb, wv, vvT2);
    k_attn<<<8192, 128, 0, stream>>>(q, kk2, vvT2, gkv, w0, b0, wb, b1, w2, b2, outh);
    k_out<<<256, 256, 0, stream>>>(outh, wo, bo, out);
}